// Round 4
// baseline (278.829 us; speedup 1.0000x reference)
//
#include <hip/hip_runtime.h>
#include <math.h>

// Shapes: B=4, N=1024, D=768, H=12, hd=64
constexpr int NSeq = 1024;
constexpr int DIM  = 768;
constexpr int NH   = 12;
constexpr int HD   = 64;

typedef __attribute__((ext_vector_type(8))) short bf16x8;   // 8 bf16 (4 VGPRs)
typedef __attribute__((ext_vector_type(4))) float f32x4;

// fp32 -> bf16 RNE
__device__ __forceinline__ short f2b(float f) {
    unsigned u = __float_as_uint(f);
    unsigned r = (u + 0x7fffu + ((u >> 16) & 1u)) >> 16;
    return (short)r;
}

// async global->LDS, 16B per lane. LDS dest = uniform base + lane*16.
__device__ __forceinline__ void glds16(const short* g, short* l) {
    __builtin_amdgcn_global_load_lds(
        (const __attribute__((address_space(1))) void*)g,
        (__attribute__((address_space(3))) void*)l, 16, 0, 0);
}

// T5 bucket, integer-exact thresholds (validated round 1)
__device__ __forceinline__ int rel_bucket(int rel) {
    int n = -rel;
    int ret = (n < 0) ? 16 : 0;
    n = (n < 0) ? -n : n;
    int k;
    if (n < 8) {
        k = n;
    } else {
        k = 8 + (n >= 12) + (n >= 16) + (n >= 23) + (n >= 32)
              + (n >= 46) + (n >= 64) + (n >= 91);
        if (k > 15) k = 15;
    }
    return ret + k;
}

// ---------------------------------------------------------------------------
__global__ __launch_bounds__(256) void cast_bf16(
    const float* __restrict__ in, short* __restrict__ out, int n)
{
    int i = (blockIdx.x * 256 + threadIdx.x) * 4;
    if (i < n) {
        float4 v = *(const float4*)(in + i);
        short4 o = make_short4(f2b(v.x), f2b(v.y), f2b(v.z), f2b(v.w));
        *(short4*)(out + i) = o;
    }
}

// W [K][Nw] fp32 -> WT [Nw][K] bf16
__global__ __launch_bounds__(256) void transpose_cast(
    const float* __restrict__ W, short* __restrict__ WT, int K, int Nw)
{
    __shared__ float t[32][33];
    int k0 = blockIdx.y * 32, n0 = blockIdx.x * 32;
    int tx = threadIdx.x & 31, ty = threadIdx.x >> 5;
#pragma unroll
    for (int r = 0; r < 4; ++r)
        t[ty + r * 8][tx] = W[(size_t)(k0 + ty + r * 8) * Nw + n0 + tx];
    __syncthreads();
#pragma unroll
    for (int r = 0; r < 4; ++r)
        WT[(size_t)(n0 + ty + r * 8) * K + k0 + tx] = f2b(t[tx][ty + r * 8]);
}

// bucketU[b][i][j] = bucket(cx_i - cx_j)*32 + bucket(cy_i - cy_j)  (i-major)
__global__ __launch_bounds__(256) void bucket_kernel(
    const float* __restrict__ coords, unsigned short* __restrict__ bucketU)
{
    int bi = blockIdx.x;                 // b*1024 + i
    int b  = bi >> 10;
    int cix = (int)(coords[(size_t)bi * 2 + 0] * 128.0f);
    int ciy = (int)(coords[(size_t)bi * 2 + 1] * 128.0f);
    int j = threadIdx.x * 4;
    const float* cp = coords + ((size_t)(b << 10) + j) * 2;
    float4 c01 = *(const float4*)cp;
    float4 c23 = *(const float4*)(cp + 4);
    ushort4 o;
    o.x = (unsigned short)(rel_bucket(cix - (int)(c01.x * 128.0f)) * 32
                         + rel_bucket(ciy - (int)(c01.y * 128.0f)));
    o.y = (unsigned short)(rel_bucket(cix - (int)(c01.z * 128.0f)) * 32
                         + rel_bucket(ciy - (int)(c01.w * 128.0f)));
    o.z = (unsigned short)(rel_bucket(cix - (int)(c23.x * 128.0f)) * 32
                         + rel_bucket(ciy - (int)(c23.y * 128.0f)));
    o.w = (unsigned short)(rel_bucket(cix - (int)(c23.z * 128.0f)) * 32
                         + rel_bucket(ciy - (int)(c23.w * 128.0f)));
    *(ushort4*)(bucketU + (size_t)bi * NSeq + j) = o;
}

// ---------------------------------------------------------------------------
// bf16 MFMA GEMM: C = A[M,K] @ BT[N,K]^T. Tile 64(M) x 128(N), BK=64,
// block 256 = 2x2 waves, wave tile 32x64. LDS staged via global_load_lds(16B)
// with XOR swizzle: chunk (row r, chunk c) -> slot r*8 + (c^(r&7)).
template <int EPI>
__global__ __launch_bounds__(256) void gemm_mfma(
    const short* __restrict__ A, const short* __restrict__ BT,
    const float* __restrict__ bias, float* __restrict__ Cout,
    short* __restrict__ qh, short* __restrict__ kh, short* __restrict__ vt,
    int M, int N, int K)
{
    __shared__ short As[64 * 64];       // 8 KB
    __shared__ short Bs[128 * 64];      // 16 KB

    const int tid  = threadIdx.x;
    const int lane = tid & 63;
    const int wave = tid >> 6;
    const int L = lane & 15, Q = lane >> 4;
    const int m0b = blockIdx.y * 64, n0b = blockIdx.x * 128;
    const int mw = (wave >> 1) * 32;
    const int nw = (wave & 1) * 64;

    // A staging: 512 chunks, 2 insts/wave; B: 1024 chunks, 4 insts/wave
    size_t aoff[2]; int la[2];
#pragma unroll
    for (int t = 0; t < 2; ++t) {
        int s = wave * 128 + t * 64 + lane;
        int r = s >> 3, c = (s & 7) ^ (r & 7);
        aoff[t] = (size_t)(m0b + r) * K + c * 8;
        la[t] = (wave * 128 + t * 64) * 8;
    }
    size_t boff[4]; int lb[4];
#pragma unroll
    for (int t = 0; t < 4; ++t) {
        int s = wave * 256 + t * 64 + lane;
        int r = s >> 3, c = (s & 7) ^ (r & 7);
        boff[t] = (size_t)(n0b + r) * K + c * 8;
        lb[t] = (wave * 256 + t * 64) * 8;
    }

    f32x4 acc[2][4];
#pragma unroll
    for (int i = 0; i < 2; ++i)
#pragma unroll
        for (int j = 0; j < 4; ++j) acc[i][j] = (f32x4){0.f, 0.f, 0.f, 0.f};

    for (int k0 = 0; k0 < K; k0 += 64) {
        __syncthreads();
#pragma unroll
        for (int t = 0; t < 2; ++t) glds16(A + aoff[t] + k0, As + la[t]);
#pragma unroll
        for (int t = 0; t < 4; ++t) glds16(BT + boff[t] + k0, Bs + lb[t]);
        __syncthreads();
#pragma unroll
        for (int ks = 0; ks < 2; ++ks) {
            bf16x8 af[2], bfr[4];
#pragma unroll
            for (int mt = 0; mt < 2; ++mt) {
                int r = mw + mt * 16 + L;
                af[mt] = *(const bf16x8*)(As + (r * 8 + ((ks * 4 + Q) ^ (r & 7))) * 8);
            }
#pragma unroll
            for (int nt = 0; nt < 4; ++nt) {
                int r = nw + nt * 16 + L;
                bfr[nt] = *(const bf16x8*)(Bs + (r * 8 + ((ks * 4 + Q) ^ (r & 7))) * 8);
            }
#pragma unroll
            for (int mt = 0; mt < 2; ++mt)
#pragma unroll
                for (int nt = 0; nt < 4; ++nt)
                    acc[mt][nt] = __builtin_amdgcn_mfma_f32_16x16x32_bf16(
                        af[mt], bfr[nt], acc[mt][nt], 0, 0, 0);
        }
    }

    const int m0 = m0b + mw, n0 = n0b + nw;
#pragma unroll
    for (int nt = 0; nt < 4; ++nt) {
        const int c0 = n0 + nt * 16;
        if (EPI == 1) {
            const int col = c0 + L;
            const float bv = bias[col];
#pragma unroll
            for (int mt = 0; mt < 2; ++mt) {
                const int r0 = m0 + mt * 16 + Q * 4;
#pragma unroll
                for (int reg = 0; reg < 4; ++reg)
                    Cout[(size_t)(r0 + reg) * N + col] = acc[mt][nt][reg] + bv;
            }
        } else {
            const int three = c0 / DIM;
            const int rem   = c0 % DIM;
            const int h     = rem >> 6;
            const int d     = (rem & 63) + L;
#pragma unroll
            for (int mt = 0; mt < 2; ++mt) {
                const int r0    = m0 + mt * 16 + Q * 4;
                const int b     = r0 >> 10;
                const int n_tok = r0 & 1023;
                if (three == 0) {        // Q: pre-scale by 1/8
                    short* p = qh + (((size_t)b * NH + h) * NSeq + n_tok) * HD + d;
#pragma unroll
                    for (int reg = 0; reg < 4; ++reg)
                        p[(size_t)reg * HD] = f2b(acc[mt][nt][reg] * 0.125f);
                } else if (three == 1) {
                    short* p = kh + (((size_t)b * NH + h) * NSeq + n_tok) * HD + d;
#pragma unroll
                    for (int reg = 0; reg < 4; ++reg)
                        p[(size_t)reg * HD] = f2b(acc[mt][nt][reg]);
                } else {                 // V transposed: vt[b][h][d][n]
                    short* p = vt + (((size_t)b * NH + h) * HD + d) * NSeq + n_tok;
#pragma unroll
                    for (int reg = 0; reg < 4; ++reg)
                        p[reg] = f2b(acc[mt][nt][reg]);
                }
            }
        }
    }
}

// ---------------------------------------------------------------------------
// Transposed-S flash attention with j-split. Block = (i-tile 64, bh, split);
// wave = 16 q-rows over a 512-wide j-half (8 iters). Static-shift softmax
// (p = exp(s-8)) -> partials combine by pure addition in combine_norm.
// All per-iter loads hoisted ahead of MFMA; V loads overlap the P-LDS wait.
// No block barriers in the j-loop; epilogue uses shfl only.
__global__ __launch_bounds__(256) void attn_mfma(
    const short* __restrict__ qh, const short* __restrict__ kh,
    const short* __restrict__ vt,
    const unsigned short* __restrict__ bucketU,   // [b][i][j]
    const float* __restrict__ elev,
    const float* __restrict__ btab_g,             // [1024][12]
    const float* __restrict__ alpha_p,
    float* __restrict__ Of,                       // [2][4096][768] fp32, unnormalized
    float* __restrict__ laux)                     // [2][48][1024] fp32
{
    __shared__ float btab[1024];
    __shared__ short P[4][16 * 72];

    const int tid  = threadIdx.x;
    const int lane = tid & 63, wave = tid >> 6;
    const int L = lane & 15, Q = lane >> 4;
    const int i0 = blockIdx.x * 64;
    const int bh = blockIdx.y;
    const int sp = blockIdx.z;                    // j-split 0/1
    const int b  = bh / NH, h = bh % NH;
    const float alpha = alpha_p[0];

    for (int p = tid; p < 1024; p += 256)
        btab[p] = btab_g[(size_t)p * NH + h];
    __syncthreads();

    const int iw = i0 + wave * 16;

    const short* qbase = qh + ((size_t)bh * NSeq + iw + L) * HD + Q * 8;
    const bf16x8 qf0 = *(const bf16x8*)qbase;
    const bf16x8 qf1 = *(const bf16x8*)(qbase + 32);

    const float er = elev[(size_t)b * NSeq + iw + L];
    float lpart = 0.0f;
    f32x4 accO[4];
#pragma unroll
    for (int t = 0; t < 4; ++t) accO[t] = (f32x4){0.f, 0.f, 0.f, 0.f};

    short* Pw = P[wave];
    const unsigned short* bubase = bucketU + ((size_t)b * NSeq + iw + L) * NSeq + sp * 512;
    const short* kbase  = kh + ((size_t)bh * NSeq + sp * 512 + L) * HD + Q * 8;
    const short* vbase  = vt + ((size_t)bh * HD + L) * NSeq + sp * 512 + Q * 8;
    const float* ejbase = elev + (size_t)b * NSeq + sp * 512;

    for (int jt = 0; jt < 8; ++jt) {
        const int j0 = jt * 64;

        // ---- hoist all independent loads for this iteration
        ushort4 bu[4];
        float4  ejv[4];
        bf16x8  kf[8];
#pragma unroll
        for (int nt = 0; nt < 4; ++nt) {
            bu[nt]  = *(const ushort4*)(bubase + j0 + nt * 16 + Q * 4);
            ejv[nt] = *(const float4*)(ejbase + j0 + nt * 16 + Q * 4);
            const short* kb = kbase + (size_t)(j0 + nt * 16) * HD;
            kf[2 * nt]     = *(const bf16x8*)kb;
            kf[2 * nt + 1] = *(const bf16x8*)(kb + 32);
        }

        // ---- S^T = MFMA(A=K, B=Q): C row = j-local, col = i = L
        f32x4 st[4];
#pragma unroll
        for (int nt = 0; nt < 4; ++nt) {
            f32x4 z = (f32x4){0.f, 0.f, 0.f, 0.f};
            z = __builtin_amdgcn_mfma_f32_16x16x32_bf16(kf[2 * nt], qf0, z, 0, 0, 0);
            st[nt] = __builtin_amdgcn_mfma_f32_16x16x32_bf16(kf[2 * nt + 1], qf1, z, 0, 0, 0);
        }

        // ---- bias + static-shift exp + pack P (A-layout: row i=L, col j)
#pragma unroll
        for (int nt = 0; nt < 4; ++nt) {
            const float ejr[4] = {ejv[nt].x, ejv[nt].y, ejv[nt].z, ejv[nt].w};
            const unsigned short bk[4] = {bu[nt].x, bu[nt].y, bu[nt].z, bu[nt].w};
            short pk[4];
            float ps = 0.0f;
#pragma unroll
            for (int reg = 0; reg < 4; ++reg) {
                float eb = -alpha * fmaxf((ejr[reg] - er) * 0.001f, 0.0f);
                eb = fminf(fmaxf(eb, -10.0f), 0.0f);
                float p = __expf(st[nt][reg] + btab[bk[reg]] + eb - 8.0f);
                ps += p;
                pk[reg] = f2b(p);
            }
            lpart += ps;
            *(short4*)&Pw[L * 72 + nt * 16 + Q * 4] =
                make_short4(pk[0], pk[1], pk[2], pk[3]);
        }

        // ---- O += P V  (P A-frag from wave-private LDS; V direct global)
        bf16x8 pf0 = *(const bf16x8*)&Pw[L * 72 + Q * 8];
        bf16x8 pf1 = *(const bf16x8*)&Pw[L * 72 + 32 + Q * 8];
        const short* vb = vbase + j0;
#pragma unroll
        for (int dt = 0; dt < 4; ++dt) {
            bf16x8 vf0 = *(const bf16x8*)(vb + (size_t)dt * 16 * NSeq);
            bf16x8 vf1 = *(const bf16x8*)(vb + (size_t)dt * 16 * NSeq + 32);
            accO[dt] = __builtin_amdgcn_mfma_f32_16x16x32_bf16(pf0, vf0, accO[dt], 0, 0, 0);
            accO[dt] = __builtin_amdgcn_mfma_f32_16x16x32_bf16(pf1, vf1, accO[dt], 0, 0, 0);
        }
    }

    // ---- partial l: sum quads of row i=L (all shfl, no barrier)
    lpart += __shfl_xor(lpart, 16, 64);
    lpart += __shfl_xor(lpart, 32, 64);
    if (Q == 0)
        laux[(((size_t)sp * 48 + bh) << 10) + iw + L] = lpart;

    // ---- store unnormalized O partial (C-layout: col=d=L, row=Q*4+reg)
    float* ofb = Of + (size_t)sp * 4096 * DIM;
#pragma unroll
    for (int reg = 0; reg < 4; ++reg) {
        const size_t row = (size_t)b * NSeq + iw + Q * 4 + reg;
#pragma unroll
        for (int dt = 0; dt < 4; ++dt)
            ofb[row * DIM + h * HD + dt * 16 + L] = accO[dt][reg];
    }
}

// ---------------------------------------------------------------------------
// Combine j-split partials: aout = bf16( (Of0+Of1) / (l0+l1) )
__global__ __launch_bounds__(256) void combine_norm(
    const float* __restrict__ Of, const float* __restrict__ laux,
    short* __restrict__ aout)
{
    const int e4 = blockIdx.x * 256 + threadIdx.x;
    const size_t e = (size_t)e4 * 4;
    const int row = (int)(e / DIM);       // b*1024+i
    const int col = (int)(e % DIM);       // h*64+d
    const int b = row >> 10, i = row & 1023, h = col >> 6;
    const int bh = b * NH + h;
    const float l0 = laux[((size_t)bh << 10) + i];
    const float l1 = laux[((size_t)(48 + bh) << 10) + i];
    const float inv = 1.0f / (l0 + l1);
    float4 a = *(const float4*)(Of + e);
    float4 c = *(const float4*)(Of + (size_t)4096 * DIM + e);
    short4 o = make_short4(f2b((a.x + c.x) * inv), f2b((a.y + c.y) * inv),
                           f2b((a.z + c.z) * inv), f2b((a.w + c.w) * inv));
    *(short4*)(aout + e) = o;
}

// ---------------------------------------------------------------------------
extern "C" void kernel_launch(void* const* d_in, const int* in_sizes, int n_in,
                              void* d_out, int out_size, void* d_ws, size_t ws_size,
                              hipStream_t stream)
{
    const float* x      = (const float*)d_in[0];
    const float* coords = (const float*)d_in[1];
    const float* elevp  = (const float*)d_in[2];
    const float* Wqkv   = (const float*)d_in[3];
    const float* Wproj  = (const float*)d_in[4];
    const float* bproj  = (const float*)d_in[5];
    const float* btab   = (const float*)d_in[6];
    const float* alpha  = (const float*)d_in[7];
    float* out = (float*)d_out;

    char* ws = (char*)d_ws;
    short* xb     = (short*)(ws);                        // 4096x768 bf16
    short* wqkvT  = (short*)(ws + 6291456);              // 2304x768 bf16
    short* wprojT = (short*)(ws + 9830400);              // 768x768 bf16
    short* qh     = (short*)(ws + 11010048);             // [48][1024][64]
    short* kh     = (short*)(ws + 17301504);
    short* vt     = (short*)(ws + 23592960);             // [48][64][1024]
    short* aout   = (short*)(ws + 29884416);             // 4096x768 bf16
    unsigned short* bucketU = (unsigned short*)(ws + 36175872); // [4][1024][1024]
    float* Of     = (float*)(ws + 44564480);             // [2][4096][768] fp32
    float* laux   = (float*)(ws + 69730304);             // [2][48][1024] fp32
    // total ws use: 70,123,520 bytes

    const int M = 4 * NSeq;

    cast_bf16<<<dim3(M * DIM / 1024), 256, 0, stream>>>(x, xb, M * DIM);
    transpose_cast<<<dim3(3 * DIM / 32, DIM / 32), 256, 0, stream>>>(
        Wqkv, wqkvT, DIM, 3 * DIM);
    transpose_cast<<<dim3(DIM / 32, DIM / 32), 256, 0, stream>>>(
        Wproj, wprojT, DIM, DIM);
    bucket_kernel<<<dim3(4 * NSeq), 256, 0, stream>>>(coords, bucketU);

    gemm_mfma<0><<<dim3(3 * DIM / 128, M / 64), 256, 0, stream>>>(
        xb, wqkvT, nullptr, nullptr, qh, kh, vt, M, 3 * DIM, DIM);

    attn_mfma<<<dim3(NSeq / 64, 4 * NH, 2), 256, 0, stream>>>(
        qh, kh, vt, bucketU, elevp, btab, alpha, Of, laux);

    combine_norm<<<dim3(M * DIM / 1024), 256, 0, stream>>>(Of, laux, aout);

    gemm_mfma<1><<<dim3(DIM / 128, M / 64), 256, 0, stream>>>(
        aout, wprojT, bproj, out, nullptr, nullptr, nullptr, M, DIM, DIM);
}

// Round 5
// 206.736 us; speedup vs baseline: 1.3487x; 1.3487x over previous
//
#include <hip/hip_runtime.h>
#include <math.h>

// Shapes: B=4, N=1024, D=768, H=12, hd=64
constexpr int NSeq = 1024;
constexpr int DIM  = 768;
constexpr int NH   = 12;
constexpr int HD   = 64;

typedef __attribute__((ext_vector_type(8))) short bf16x8;   // 8 bf16 (4 VGPRs)
typedef __attribute__((ext_vector_type(4))) float f32x4;

// fp32 -> bf16 RNE
__device__ __forceinline__ short f2b(float f) {
    unsigned u = __float_as_uint(f);
    unsigned r = (u + 0x7fffu + ((u >> 16) & 1u)) >> 16;
    return (short)r;
}

// async global->LDS, 16B per lane. LDS dest = uniform base + lane*16.
__device__ __forceinline__ void glds16(const short* g, short* l) {
    __builtin_amdgcn_global_load_lds(
        (const __attribute__((address_space(1))) void*)g,
        (__attribute__((address_space(3))) void*)l, 16, 0, 0);
}

// T5 bucket, integer-exact thresholds (validated round 1)
__device__ __forceinline__ int rel_bucket(int rel) {
    int n = -rel;
    int ret = (n < 0) ? 16 : 0;
    n = (n < 0) ? -n : n;
    int k;
    if (n < 8) {
        k = n;
    } else {
        k = 8 + (n >= 12) + (n >= 16) + (n >= 23) + (n >= 32)
              + (n >= 46) + (n >= 64) + (n >= 91);
        if (k > 15) k = 15;
    }
    return ret + k;
}

// ---------------------------------------------------------------------------
__global__ __launch_bounds__(256) void cast_bf16(
    const float* __restrict__ in, short* __restrict__ out, int n)
{
    int i = (blockIdx.x * 256 + threadIdx.x) * 4;
    if (i < n) {
        float4 v = *(const float4*)(in + i);
        short4 o = make_short4(f2b(v.x), f2b(v.y), f2b(v.z), f2b(v.w));
        *(short4*)(out + i) = o;
    }
}

// W [K][Nw] fp32 -> WT [Nw][K] bf16
__global__ __launch_bounds__(256) void transpose_cast(
    const float* __restrict__ W, short* __restrict__ WT, int K, int Nw)
{
    __shared__ float t[32][33];
    int k0 = blockIdx.y * 32, n0 = blockIdx.x * 32;
    int tx = threadIdx.x & 31, ty = threadIdx.x >> 5;
#pragma unroll
    for (int r = 0; r < 4; ++r)
        t[ty + r * 8][tx] = W[(size_t)(k0 + ty + r * 8) * Nw + n0 + tx];
    __syncthreads();
#pragma unroll
    for (int r = 0; r < 4; ++r)
        WT[(size_t)(n0 + ty + r * 8) * K + k0 + tx] = f2b(t[tx][ty + r * 8]);
}

// ---------------------------------------------------------------------------
// upack: h-independent bias metadata, packed per MFMA S^T fragment position.
// U[b][i16][jt][nt][lane] = uint4; element reg: bk | (eb16 << 16) where
// bk = bucket(ci-cj) pair index, eb16 = round(min(10, a*relu(de))*6553.5).
// Attn reads one coalesced uint4 per (nt): 1 KB/wave-inst, fully dense.
__global__ __launch_bounds__(256) void upack_kernel(
    const float* __restrict__ coords, const float* __restrict__ elev,
    const float* __restrict__ alpha_p, unsigned int* __restrict__ U)
{
    const int blk  = blockIdx.x;         // b*64 + i16
    const int b    = blk >> 6;
    const int i16  = blk & 63;
    const int tid  = threadIdx.x;
    const int lane = tid & 63, wv = tid >> 6;
    const int L = lane & 15, Q = lane >> 4;
    const float alpha = alpha_p[0];

    const int i = (i16 << 4) + L;
    const float2 cf = *(const float2*)&coords[(((size_t)b << 10) + i) * 2];
    const int cix = (int)(cf.x * 128.0f);
    const int ciy = (int)(cf.y * 128.0f);
    const float er = elev[((size_t)b << 10) + i];

#pragma unroll
    for (int jj = 0; jj < 4; ++jj) {
        const int jt = wv * 4 + jj;
#pragma unroll
        for (int nt = 0; nt < 4; ++nt) {
            const int j0q = jt * 64 + nt * 16 + Q * 4;
            float4 c01 = *(const float4*)&coords[(((size_t)b << 10) + j0q) * 2];
            float4 c23 = *(const float4*)&coords[(((size_t)b << 10) + j0q + 2) * 2];
            float4 ej  = *(const float4*)&elev[((size_t)b << 10) + j0q];
            const float cjx[4] = {c01.x, c01.z, c23.x, c23.z};
            const float cjy[4] = {c01.y, c01.w, c23.y, c23.w};
            const float ejv[4] = {ej.x, ej.y, ej.z, ej.w};
            unsigned int uo[4];
#pragma unroll
            for (int reg = 0; reg < 4; ++reg) {
                int bk = rel_bucket(cix - (int)(cjx[reg] * 128.0f)) * 32
                       + rel_bucket(ciy - (int)(cjy[reg] * 128.0f));
                float ebp = fminf(10.0f,
                    fmaxf(0.0f, alpha * fmaxf((ejv[reg] - er) * 0.001f, 0.0f)));
                unsigned int q = (unsigned int)lrintf(ebp * 6553.5f);
                uo[reg] = (unsigned int)bk | (q << 16);
            }
            size_t base = ((((size_t)blk * 16 + jt) * 4 + nt) * 64 + lane) * 4;
            *(uint4*)(U + base) = make_uint4(uo[0], uo[1], uo[2], uo[3]);
        }
    }
}

// ---------------------------------------------------------------------------
// bf16 MFMA GEMM: C = A[M,K] @ BT[N,K]^T. Tile 128x128, BK=64, block 256 =
// 2x2 waves (wave tile 64x64). LDS staged via global_load_lds(16B) with XOR
// swizzle: chunk (row r, chunk c) -> slot r*8 + (c^(r&7)).
template <int EPI>
__global__ __launch_bounds__(256) void gemm_mfma(
    const short* __restrict__ A, const short* __restrict__ BT,
    const float* __restrict__ bias, float* __restrict__ Cout,
    short* __restrict__ qh, short* __restrict__ kh, short* __restrict__ vt,
    int M, int N, int K)
{
    __shared__ short As[128 * 64];      // 16 KB
    __shared__ short Bs[128 * 64];      // 16 KB

    const int tid  = threadIdx.x;
    const int lane = tid & 63;
    const int wave = tid >> 6;
    const int L = lane & 15, Q = lane >> 4;
    const int m0b = blockIdx.y * 128, n0b = blockIdx.x * 128;
    const int mw = (wave >> 1) * 64;
    const int nw = (wave & 1) * 64;

    size_t aoff[4], boff[4];
    int lbase[4];
#pragma unroll
    for (int t = 0; t < 4; ++t) {
        int s = wave * 256 + t * 64 + lane;
        int r = s >> 3, c = (s & 7) ^ (r & 7);
        aoff[t] = (size_t)(m0b + r) * K + c * 8;
        boff[t] = (size_t)(n0b + r) * K + c * 8;
        lbase[t] = (wave * 256 + t * 64) * 8;
    }

    f32x4 acc[4][4];
#pragma unroll
    for (int i = 0; i < 4; ++i)
#pragma unroll
        for (int j = 0; j < 4; ++j) acc[i][j] = (f32x4){0.f, 0.f, 0.f, 0.f};

    for (int k0 = 0; k0 < K; k0 += 64) {
        __syncthreads();
#pragma unroll
        for (int t = 0; t < 4; ++t) {
            glds16(A  + aoff[t] + k0, As + lbase[t]);
            glds16(BT + boff[t] + k0, Bs + lbase[t]);
        }
        __syncthreads();
#pragma unroll
        for (int ks = 0; ks < 2; ++ks) {
            bf16x8 af[4], bfr[4];
#pragma unroll
            for (int mt = 0; mt < 4; ++mt) {
                int r = mw + mt * 16 + L;
                af[mt] = *(const bf16x8*)(As + (r * 8 + ((ks * 4 + Q) ^ (r & 7))) * 8);
            }
#pragma unroll
            for (int nt = 0; nt < 4; ++nt) {
                int r = nw + nt * 16 + L;
                bfr[nt] = *(const bf16x8*)(Bs + (r * 8 + ((ks * 4 + Q) ^ (r & 7))) * 8);
            }
#pragma unroll
            for (int mt = 0; mt < 4; ++mt)
#pragma unroll
                for (int nt = 0; nt < 4; ++nt)
                    acc[mt][nt] = __builtin_amdgcn_mfma_f32_16x16x32_bf16(
                        af[mt], bfr[nt], acc[mt][nt], 0, 0, 0);
        }
    }

    const int m0 = m0b + mw, n0 = n0b + nw;
#pragma unroll
    for (int nt = 0; nt < 4; ++nt) {
        const int c0 = n0 + nt * 16;
        if (EPI == 1) {
            const int col = c0 + L;
            const float bv = bias[col];
#pragma unroll
            for (int mt = 0; mt < 4; ++mt) {
                const int r0 = m0 + mt * 16 + Q * 4;
#pragma unroll
                for (int reg = 0; reg < 4; ++reg)
                    Cout[(size_t)(r0 + reg) * N + col] = acc[mt][nt][reg] + bv;
            }
        } else {
            const int three = c0 / DIM;
            const int rem   = c0 % DIM;
            const int h     = rem >> 6;
            const int d     = (rem & 63) + L;
#pragma unroll
            for (int mt = 0; mt < 4; ++mt) {
                const int r0    = m0 + mt * 16 + Q * 4;
                const int b     = r0 >> 10;
                const int n_tok = r0 & 1023;
                if (three == 0) {        // Q: pre-scale by hd^-0.5
                    short* p = qh + (((size_t)b * NH + h) * NSeq + n_tok) * HD + d;
#pragma unroll
                    for (int reg = 0; reg < 4; ++reg)
                        p[(size_t)reg * HD] = f2b(acc[mt][nt][reg] * 0.125f);
                } else if (three == 1) {
                    short* p = kh + (((size_t)b * NH + h) * NSeq + n_tok) * HD + d;
#pragma unroll
                    for (int reg = 0; reg < 4; ++reg)
                        p[(size_t)reg * HD] = f2b(acc[mt][nt][reg]);
                } else {                 // V transposed: vt[b][h][d][n]
                    short* p = vt + (((size_t)b * NH + h) * HD + d) * NSeq + n_tok;
#pragma unroll
                    for (int reg = 0; reg < 4; ++reg)
                        p[reg] = f2b(acc[mt][nt][reg]);
                }
            }
        }
    }
}

// ---------------------------------------------------------------------------
// Transposed-S flash attention, v5: K/V tiles staged per-block via glds
// (8 KB each, XOR swizzle, m97 2-barrier loop) so the 4 waves stop issuing
// 4x-redundant sparse global frag loads. Bias metadata from U (coalesced
// uint4: bucket + quantized elev-bias). Static-shift softmax p = exp(s-8).
// P round-trips through wave-private LDS. btab gather stays (known cost).
__global__ __launch_bounds__(256) void attn_mfma(
    const short* __restrict__ qh, const short* __restrict__ kh,
    const short* __restrict__ vt,
    const unsigned int* __restrict__ U,
    const float* __restrict__ btab_g,             // [1024][12]
    short* __restrict__ aout)                     // [4096][768] bf16
{
    __shared__ short Ks[64 * 64];   // 8 KB
    __shared__ short Vs[64 * 64];   // 8 KB
    __shared__ float btab[1024];    // 4 KB
    __shared__ short P[4][16 * 72]; // 9 KB
    __shared__ float lsh[64];

    const int tid  = threadIdx.x;
    const int lane = tid & 63, wave = tid >> 6;
    const int L = lane & 15, Q = lane >> 4;
    const int i0 = blockIdx.x * 64;
    const int bh = blockIdx.y;
    const int b  = bh / NH, h = bh % NH;

    for (int p = tid; p < 1024; p += 256)
        btab[p] = btab_g[(size_t)p * NH + h];

    const int iw = i0 + wave * 16;

    // Q as B-operand: B[k=d][n=i=L]
    const short* qbase = qh + ((size_t)bh * NSeq + iw + L) * HD + Q * 8;
    const bf16x8 qf0 = *(const bf16x8*)qbase;
    const bf16x8 qf1 = *(const bf16x8*)(qbase + 32);

    // staging addresses (2 K-insts + 2 V-insts per wave per iter)
    size_t kgo[2], vgo[2];
    int lb[2];
#pragma unroll
    for (int t = 0; t < 2; ++t) {
        int s = wave * 128 + t * 64 + lane;
        int r = s >> 3, c = (s & 7) ^ (r & 7);
        kgo[t] = ((size_t)bh * NSeq + r) * HD + c * 8;     // + j0*HD
        vgo[t] = ((size_t)bh * HD + r) * NSeq + c * 8;     // + j0
        lb[t] = (wave * 128 + t * 64) * 8;
    }

    // U base for this wave's i16
    const int i16g = (b * 64) + (blockIdx.x * 4 + wave);
    const unsigned int* Ub = U + (size_t)i16g * 16 * 4 * 256 + lane * 4;

    float lpart = 0.0f;
    f32x4 accO[4];
#pragma unroll
    for (int t = 0; t < 4; ++t) accO[t] = (f32x4){0.f, 0.f, 0.f, 0.f};

    short* Pw = P[wave];
    const float ec = 1.0f / 6553.5f;

    for (int jt = 0; jt < 16; ++jt) {
        const int j0 = jt * 64;

        __syncthreads();   // prev compute done reading Ks/Vs (also covers btab fill)
#pragma unroll
        for (int t = 0; t < 2; ++t) {
            glds16(kh + kgo[t] + (size_t)j0 * HD, Ks + lb[t]);
            glds16(vt + vgo[t] + j0, Vs + lb[t]);
        }
        __syncthreads();   // staged data visible

        // ---- S^T = MFMA(A=K from LDS, B=Q): C row = j-local, col = i = L
        f32x4 st[4];
#pragma unroll
        for (int nt = 0; nt < 4; ++nt) {
            int r = nt * 16 + L;
            bf16x8 kf0 = *(const bf16x8*)(Ks + (r * 8 + (Q ^ (r & 7))) * 8);
            bf16x8 kf1 = *(const bf16x8*)(Ks + (r * 8 + ((4 + Q) ^ (r & 7))) * 8);
            f32x4 z = (f32x4){0.f, 0.f, 0.f, 0.f};
            z = __builtin_amdgcn_mfma_f32_16x16x32_bf16(kf0, qf0, z, 0, 0, 0);
            st[nt] = __builtin_amdgcn_mfma_f32_16x16x32_bf16(kf1, qf1, z, 0, 0, 0);
        }

        // ---- bias (U + btab gather) + static-shift exp + pack P
#pragma unroll
        for (int nt = 0; nt < 4; ++nt) {
            uint4 u = *(const uint4*)(Ub + ((size_t)jt * 4 + nt) * 256);
            const unsigned int uv[4] = {u.x, u.y, u.z, u.w};
            short pk[4];
            float ps = 0.0f;
#pragma unroll
            for (int reg = 0; reg < 4; ++reg) {
                float bt = btab[uv[reg] & 1023];
                float eb = (float)(uv[reg] >> 16) * ec;
                float p = __expf(st[nt][reg] + bt - eb - 8.0f);
                ps += p;
                pk[reg] = f2b(p);
            }
            lpart += ps;
            *(short4*)&Pw[L * 72 + nt * 16 + Q * 4] =
                make_short4(pk[0], pk[1], pk[2], pk[3]);
        }

        // ---- O += P V (P A-frag wave-private; V B-frag from LDS)
        bf16x8 pf0 = *(const bf16x8*)&Pw[L * 72 + Q * 8];
        bf16x8 pf1 = *(const bf16x8*)&Pw[L * 72 + 32 + Q * 8];
#pragma unroll
        for (int dt = 0; dt < 4; ++dt) {
            int r = dt * 16 + L;
            bf16x8 vf0 = *(const bf16x8*)(Vs + (r * 8 + (Q ^ (r & 7))) * 8);
            bf16x8 vf1 = *(const bf16x8*)(Vs + (r * 8 + ((4 + Q) ^ (r & 7))) * 8);
            accO[dt] = __builtin_amdgcn_mfma_f32_16x16x32_bf16(pf0, vf0, accO[dt], 0, 0, 0);
            accO[dt] = __builtin_amdgcn_mfma_f32_16x16x32_bf16(pf1, vf1, accO[dt], 0, 0, 0);
        }
    }

    // ---- l: in-lane partial + cross-quad shfl, share rows via LDS
    lpart += __shfl_xor(lpart, 16, 64);
    lpart += __shfl_xor(lpart, 32, 64);
    lsh[wave * 16 + L] = lpart;
    __syncthreads();
    float4 lv = *(const float4*)&lsh[wave * 16 + Q * 4];
    const float linv[4] = {1.0f / lv.x, 1.0f / lv.y, 1.0f / lv.z, 1.0f / lv.w};

    // O C-layout: col = d = L, row = i-local = Q*4+reg
#pragma unroll
    for (int reg = 0; reg < 4; ++reg) {
        const size_t row = (size_t)b * NSeq + iw + Q * 4 + reg;
#pragma unroll
        for (int dt = 0; dt < 4; ++dt)
            aout[row * DIM + h * HD + dt * 16 + L] = f2b(accO[dt][reg] * linv[reg]);
    }
}

// ---------------------------------------------------------------------------
extern "C" void kernel_launch(void* const* d_in, const int* in_sizes, int n_in,
                              void* d_out, int out_size, void* d_ws, size_t ws_size,
                              hipStream_t stream)
{
    const float* x      = (const float*)d_in[0];
    const float* coords = (const float*)d_in[1];
    const float* elevp  = (const float*)d_in[2];
    const float* Wqkv   = (const float*)d_in[3];
    const float* Wproj  = (const float*)d_in[4];
    const float* bproj  = (const float*)d_in[5];
    const float* btab   = (const float*)d_in[6];
    const float* alpha  = (const float*)d_in[7];
    float* out = (float*)d_out;

    char* ws = (char*)d_ws;
    short* xb     = (short*)(ws);                        // 4096x768 bf16
    short* wqkvT  = (short*)(ws + 6291456);              // 2304x768 bf16
    short* wprojT = (short*)(ws + 9830400);              // 768x768 bf16
    short* qh     = (short*)(ws + 11010048);             // [48][1024][64]
    short* kh     = (short*)(ws + 17301504);
    short* vt     = (short*)(ws + 23592960);             // [48][64][1024]
    short* aout   = (short*)(ws + 29884416);             // 4096x768 bf16
    unsigned int* U = (unsigned int*)(ws + 36175872);    // 16.78 MB packed bias
    // total ws use: 52,953,088 bytes

    const int M = 4 * NSeq;

    cast_bf16<<<dim3(M * DIM / 1024), 256, 0, stream>>>(x, xb, M * DIM);
    transpose_cast<<<dim3(3 * DIM / 32, DIM / 32), 256, 0, stream>>>(
        Wqkv, wqkvT, DIM, 3 * DIM);
    transpose_cast<<<dim3(DIM / 32, DIM / 32), 256, 0, stream>>>(
        Wproj, wprojT, DIM, DIM);
    upack_kernel<<<dim3(4 * 64), 256, 0, stream>>>(coords, elevp, alpha, U);

    gemm_mfma<0><<<dim3(3 * DIM / 128, M / 128), 256, 0, stream>>>(
        xb, wqkvT, nullptr, nullptr, qh, kh, vt, M, 3 * DIM, DIM);

    attn_mfma<<<dim3(NSeq / 64, 4 * NH), 256, 0, stream>>>(
        qh, kh, vt, U, btab, aout);

    gemm_mfma<1><<<dim3(DIM / 128, M / 128), 256, 0, stream>>>(
        aout, wprojT, bproj, out, nullptr, nullptr, nullptr, M, DIM, DIM);
}

// Round 7
// 203.199 us; speedup vs baseline: 1.3722x; 1.0174x over previous
//
#include <hip/hip_runtime.h>
#include <hip/hip_bf16.h>
#include <math.h>

// Shapes: B=4, N=1024, D=768, H=12, hd=64
constexpr int NSeq = 1024;
constexpr int DIM  = 768;
constexpr int NH   = 12;
constexpr int HD   = 64;

// exp2-domain softmax constants
#define LOG2E     1.4426950408889634f
#define QSCALE    0.18033688011112042f   /* 0.125 * log2e */
#define BSHIFT    11.541560327111707f    /* 8 * log2e */
#define EBQ       6551.278150676693f     /* log2e * 4541 (16-bit quant scale) */
#define EBDEC     (-1.0f / 4541.0f)

#if __has_builtin(__builtin_amdgcn_exp2f)
#define EXP2F(x) __builtin_amdgcn_exp2f(x)
#else
#define EXP2F(x) exp2f(x)
#endif

typedef __attribute__((ext_vector_type(8))) short bf16x8;   // 8 bf16 (4 VGPRs)
typedef __attribute__((ext_vector_type(4))) float f32x4;

// fp32 -> bf16 RNE (scalar)
__device__ __forceinline__ short f2b(float f) {
    unsigned u = __float_as_uint(f);
    unsigned r = (u + 0x7fffu + ((u >> 16) & 1u)) >> 16;
    return (short)r;
}
// packed pair via native v_cvt_pk_bf16_f32
__device__ __forceinline__ unsigned pk2(float a, float b) {
    __hip_bfloat162 h = __float22bfloat162_rn(float2{a, b});
    return *reinterpret_cast<unsigned*>(&h);
}

// async global->LDS, 16B per lane. LDS dest = uniform base + lane*16.
__device__ __forceinline__ void glds16(const short* g, short* l) {
    __builtin_amdgcn_global_load_lds(
        (const __attribute__((address_space(1))) void*)g,
        (__attribute__((address_space(3))) void*)l, 16, 0, 0);
}

// T5 bucket, integer-exact thresholds (validated round 1)
__device__ __forceinline__ int rel_bucket(int rel) {
    int n = -rel;
    int ret = (n < 0) ? 16 : 0;
    n = (n < 0) ? -n : n;
    int k;
    if (n < 8) {
        k = n;
    } else {
        k = 8 + (n >= 12) + (n >= 16) + (n >= 23) + (n >= 32)
              + (n >= 46) + (n >= 64) + (n >= 91);
        if (k > 15) k = 15;
    }
    return ret + k;
}

// ---------------------------------------------------------------------------
// Fused prep: [0,3072) cast x->bf16 | [3072,4800) Wqkv^T | [4800,5376) Wproj^T
// | [5376,5632) upack (bucket + quantized elev-bias, MFMA-fragment order).
constexpr int PREP_CAST = 3072;
constexpr int PREP_WQKV = PREP_CAST + 1728;   // 72 x 24 tiles
constexpr int PREP_WPRJ = PREP_WQKV + 576;    // 24 x 24 tiles
constexpr int PREP_TOT  = PREP_WPRJ + 256;

__global__ __launch_bounds__(256) void prep_kernel(
    const float* __restrict__ x, short* __restrict__ xb,
    const float* __restrict__ Wqkv, short* __restrict__ wqkvT,
    const float* __restrict__ Wproj, short* __restrict__ wprojT,
    const float* __restrict__ coords, const float* __restrict__ elev,
    const float* __restrict__ alpha_p, unsigned int* __restrict__ U)
{
    __shared__ float t[32][33];
    const int bx  = blockIdx.x;
    const int tid = threadIdx.x;

    if (bx < PREP_CAST) {
        int i = (bx * 256 + tid) * 4;
        float4 v = *(const float4*)(x + i);
        *(short4*)(xb + i) = make_short4(f2b(v.x), f2b(v.y), f2b(v.z), f2b(v.w));
        return;
    }
    if (bx < PREP_WPRJ) {
        const float* W; short* WT; int K, Nw, idx;
        if (bx < PREP_WQKV) { W = Wqkv; WT = wqkvT; K = DIM; Nw = 3 * DIM; idx = bx - PREP_CAST; }
        else                { W = Wproj; WT = wprojT; K = DIM; Nw = DIM;     idx = bx - PREP_WQKV; }
        const int nt = idx % (Nw / 32), kt = idx / (Nw / 32);
        const int k0 = kt * 32, n0 = nt * 32;
        const int tx = tid & 31, ty = tid >> 5;
#pragma unroll
        for (int r = 0; r < 4; ++r)
            t[ty + r * 8][tx] = W[(size_t)(k0 + ty + r * 8) * Nw + n0 + tx];
        __syncthreads();
#pragma unroll
        for (int r = 0; r < 4; ++r)
            WT[(size_t)(n0 + ty + r * 8) * K + k0 + tx] = f2b(t[tx][ty + r * 8]);
        return;
    }
    // ---- upack
    const int blk  = bx - PREP_WPRJ;      // b*64 + i16
    const int b    = blk >> 6;
    const int lane = tid & 63, wv = tid >> 6;
    const int L = lane & 15, Q = lane >> 4;
    const float alpha = alpha_p[0];

    const int i = ((blk & 63) << 4) + L;
    const float2 cf = *(const float2*)&coords[(((size_t)b << 10) + i) * 2];
    const int cix = (int)(cf.x * 128.0f);
    const int ciy = (int)(cf.y * 128.0f);
    const float er = elev[((size_t)b << 10) + i];

#pragma unroll
    for (int jj = 0; jj < 4; ++jj) {
        const int jt = wv * 4 + jj;
#pragma unroll
        for (int nt = 0; nt < 4; ++nt) {
            const int j0q = jt * 64 + nt * 16 + Q * 4;
            float4 c01 = *(const float4*)&coords[(((size_t)b << 10) + j0q) * 2];
            float4 c23 = *(const float4*)&coords[(((size_t)b << 10) + j0q + 2) * 2];
            float4 ej  = *(const float4*)&elev[((size_t)b << 10) + j0q];
            const float cjx[4] = {c01.x, c01.z, c23.x, c23.z};
            const float cjy[4] = {c01.y, c01.w, c23.y, c23.w};
            const float ejv[4] = {ej.x, ej.y, ej.z, ej.w};
            unsigned int uo[4];
#pragma unroll
            for (int reg = 0; reg < 4; ++reg) {
                int bk = rel_bucket(cix - (int)(cjx[reg] * 128.0f)) * 32
                       + rel_bucket(ciy - (int)(cjy[reg] * 128.0f));
                float ebp = fminf(10.0f,
                    fmaxf(0.0f, alpha * fmaxf((ejv[reg] - er) * 0.001f, 0.0f)));
                unsigned int q = (unsigned int)lrintf(ebp * EBQ);
                uo[reg] = (unsigned int)bk | (q << 16);
            }
            size_t base = ((((size_t)blk * 16 + jt) * 4 + nt) * 64 + lane) * 4;
            *(uint4*)(U + base) = make_uint4(uo[0], uo[1], uo[2], uo[3]);
        }
    }
}

// ---------------------------------------------------------------------------
// bf16 MFMA GEMM: C = A[M,K] @ BT[N,K]^T. Tile 64(M) x 128(N), BK=64,
// block 256 = 2x2 waves, wave tile 32x64. glds(16B) staging, XOR swizzle.
template <int EPI>
__global__ __launch_bounds__(256) void gemm_mfma(
    const short* __restrict__ A, const short* __restrict__ BT,
    const float* __restrict__ bias, float* __restrict__ Cout,
    short* __restrict__ qh, short* __restrict__ kh, short* __restrict__ vt,
    int M, int N, int K)
{
    __shared__ short As[64 * 64];       // 8 KB
    __shared__ short Bs[128 * 64];      // 16 KB

    const int tid  = threadIdx.x;
    const int lane = tid & 63;
    const int wave = tid >> 6;
    const int L = lane & 15, Q = lane >> 4;
    const int m0b = blockIdx.y * 64, n0b = blockIdx.x * 128;
    const int mw = (wave >> 1) * 32;
    const int nw = (wave & 1) * 64;

    size_t aoff[2]; int la[2];
#pragma unroll
    for (int t = 0; t < 2; ++t) {
        int s = wave * 128 + t * 64 + lane;
        int r = s >> 3, c = (s & 7) ^ (r & 7);
        aoff[t] = (size_t)(m0b + r) * K + c * 8;
        la[t] = (wave * 128 + t * 64) * 8;
    }
    size_t boff[4]; int lb[4];
#pragma unroll
    for (int t = 0; t < 4; ++t) {
        int s = wave * 256 + t * 64 + lane;
        int r = s >> 3, c = (s & 7) ^ (r & 7);
        boff[t] = (size_t)(n0b + r) * K + c * 8;
        lb[t] = (wave * 256 + t * 64) * 8;
    }

    f32x4 acc[2][4];
#pragma unroll
    for (int i = 0; i < 2; ++i)
#pragma unroll
        for (int j = 0; j < 4; ++j) acc[i][j] = (f32x4){0.f, 0.f, 0.f, 0.f};

    for (int k0 = 0; k0 < K; k0 += 64) {
        __syncthreads();
#pragma unroll
        for (int t = 0; t < 2; ++t) glds16(A + aoff[t] + k0, As + la[t]);
#pragma unroll
        for (int t = 0; t < 4; ++t) glds16(BT + boff[t] + k0, Bs + lb[t]);
        __syncthreads();
#pragma unroll
        for (int ks = 0; ks < 2; ++ks) {
            bf16x8 af[2], bfr[4];
#pragma unroll
            for (int mt = 0; mt < 2; ++mt) {
                int r = mw + mt * 16 + L;
                af[mt] = *(const bf16x8*)(As + (r * 8 + ((ks * 4 + Q) ^ (r & 7))) * 8);
            }
#pragma unroll
            for (int nt = 0; nt < 4; ++nt) {
                int r = nw + nt * 16 + L;
                bfr[nt] = *(const bf16x8*)(Bs + (r * 8 + ((ks * 4 + Q) ^ (r & 7))) * 8);
            }
#pragma unroll
            for (int mt = 0; mt < 2; ++mt)
#pragma unroll
                for (int nt = 0; nt < 4; ++nt)
                    acc[mt][nt] = __builtin_amdgcn_mfma_f32_16x16x32_bf16(
                        af[mt], bfr[nt], acc[mt][nt], 0, 0, 0);
        }
    }

    const int m0 = m0b + mw, n0 = n0b + nw;
#pragma unroll
    for (int nt = 0; nt < 4; ++nt) {
        const int c0 = n0 + nt * 16;
        if (EPI == 1) {
            const int col = c0 + L;
            const float bv = bias[col];
#pragma unroll
            for (int mt = 0; mt < 2; ++mt) {
                const int r0 = m0 + mt * 16 + Q * 4;
#pragma unroll
                for (int reg = 0; reg < 4; ++reg)
                    Cout[(size_t)(r0 + reg) * N + col] = acc[mt][nt][reg] + bv;
            }
        } else {
            const int three = c0 / DIM;
            const int rem   = c0 % DIM;
            const int h     = rem >> 6;
            const int d     = (rem & 63) + L;
#pragma unroll
            for (int mt = 0; mt < 2; ++mt) {
                const int r0    = m0 + mt * 16 + Q * 4;
                const int b     = r0 >> 10;
                const int n_tok = r0 & 1023;
                if (three == 0) {        // Q: pre-scale by 0.125*log2e (exp2 softmax)
                    short* p = qh + (((size_t)b * NH + h) * NSeq + n_tok) * HD + d;
#pragma unroll
                    for (int reg = 0; reg < 4; ++reg)
                        p[(size_t)reg * HD] = f2b(acc[mt][nt][reg] * QSCALE);
                } else if (three == 1) {
                    short* p = kh + (((size_t)b * NH + h) * NSeq + n_tok) * HD + d;
#pragma unroll
                    for (int reg = 0; reg < 4; ++reg)
                        p[(size_t)reg * HD] = f2b(acc[mt][nt][reg]);
                } else {                 // V transposed: vt[b][h][d][n]
                    short* p = vt + (((size_t)b * NH + h) * HD + d) * NSeq + n_tok;
#pragma unroll
                    for (int reg = 0; reg < 4; ++reg)
                        p[reg] = f2b(acc[mt][nt][reg]);
                }
            }
        }
    }
}

// ---------------------------------------------------------------------------
// Transposed-S flash attention, v6.1: j-tile 128, exp2-domain static-shift
// softmax, native bf16 pack, shfl-only epilogue. K/V staged via glds + XOR
// swizzle. FIX vs v6: Vs rows have 16 chunks -> the B-frag chunk indices for
// half jh are jh*8+Q (vf0) and jh*8+4+Q (vf1); v6 used jh*4+Q / jh*4+8+Q,
// swapping V columns j in [32,64) with [64,96).
__global__ __launch_bounds__(256) void attn_mfma(
    const short* __restrict__ qh, const short* __restrict__ kh,
    const short* __restrict__ vt,
    const unsigned int* __restrict__ U,
    const float* __restrict__ btab_g,             // [1024][12]
    short* __restrict__ aout)                     // [4096][768] bf16
{
    __shared__ short Ks[128 * 64];  // 16 KB, rows=j, 8 chunks/row
    __shared__ short Vs[64 * 128];  // 16 KB, rows=d, 16 chunks/row
    __shared__ float btab[1024];    // 4 KB (pre-scaled: *log2e - 8*log2e)
    __shared__ short P[4][16 * 72]; // 9 KB

    const int tid  = threadIdx.x;
    const int lane = tid & 63, wave = tid >> 6;
    const int L = lane & 15, Q = lane >> 4;
    const int i0 = blockIdx.x * 64;
    const int bh = blockIdx.y;
    const int b  = bh / NH, h = bh % NH;

    for (int p = tid; p < 1024; p += 256)
        btab[p] = btab_g[(size_t)p * NH + h] * LOG2E - BSHIFT;

    const int iw = i0 + wave * 16;

    // Q as B-operand: B[k=d][n=i=L]  (pre-scaled by 0.125*log2e in gemm0)
    const short* qbase = qh + ((size_t)bh * NSeq + iw + L) * HD + Q * 8;
    const bf16x8 qf0 = *(const bf16x8*)qbase;
    const bf16x8 qf1 = *(const bf16x8*)(qbase + 32);

    // staging addresses: K 4 insts/wave, V 4 insts/wave per 128-j iter
    size_t kgo[4], vgo[4];
    int lsl[4];
#pragma unroll
    for (int t = 0; t < 4; ++t) {
        int s = wave * 256 + t * 64 + lane;            // 0..1023
        int kr = s >> 3, kc = (s & 7) ^ (kr & 7);
        kgo[t] = ((size_t)bh * NSeq + kr) * HD + kc * 8;       // + j0*HD
        int vr = s >> 4, vc = (s & 15) ^ (vr & 15);
        vgo[t] = ((size_t)bh * HD + vr) * NSeq + vc * 8;       // + j0
        lsl[t] = s * 8;
    }

    const int i16g = (b * 64) + (blockIdx.x * 4 + wave);
    const unsigned int* Ub = U + (size_t)i16g * 16 * 4 * 256 + lane * 4;

    float lpart = 0.0f;
    f32x4 accO[4];
#pragma unroll
    for (int t = 0; t < 4; ++t) accO[t] = (f32x4){0.f, 0.f, 0.f, 0.f};

    short* Pw = P[wave];

    for (int jt = 0; jt < 8; ++jt) {
        const int j0 = jt * 128;
        __syncthreads();   // prev iter's Ks/Vs reads done (also covers btab fill)
#pragma unroll
        for (int t = 0; t < 4; ++t) glds16(kh + kgo[t] + (size_t)j0 * HD, Ks + lsl[t]);
#pragma unroll
        for (int t = 0; t < 4; ++t) glds16(vt + vgo[t] + j0, Vs + lsl[t]);
        __syncthreads();   // staged data visible

#pragma unroll
        for (int jh = 0; jh < 2; ++jh) {
            // ---- S^T = MFMA(A=K from LDS, B=Q): C row = j-local, col = i = L
            f32x4 st[4];
#pragma unroll
            for (int nt = 0; nt < 4; ++nt) {
                int r = jh * 64 + nt * 16 + L;
                bf16x8 kf0 = *(const bf16x8*)(Ks + (r * 8 + (Q ^ (L & 7))) * 8);
                bf16x8 kf1 = *(const bf16x8*)(Ks + (r * 8 + ((4 + Q) ^ (L & 7))) * 8);
                f32x4 z = (f32x4){0.f, 0.f, 0.f, 0.f};
                z = __builtin_amdgcn_mfma_f32_16x16x32_bf16(kf0, qf0, z, 0, 0, 0);
                st[nt] = __builtin_amdgcn_mfma_f32_16x16x32_bf16(kf1, qf1, z, 0, 0, 0);
            }

            // ---- bias + exp2 + pack P (A-layout: row i=L, col j)
#pragma unroll
            for (int nt = 0; nt < 4; ++nt) {
                uint4 u = *(const uint4*)(Ub + (((size_t)jt * 2 + jh) * 4 + nt) * 256);
                const unsigned int uv[4] = {u.x, u.y, u.z, u.w};
                float pv[4];
                float ps = 0.0f;
#pragma unroll
                for (int reg = 0; reg < 4; ++reg) {
                    float arg = st[nt][reg] + btab[uv[reg] & 1023];
                    arg = fmaf((float)(uv[reg] >> 16), EBDEC, arg);
                    float p = EXP2F(arg);
                    ps += p;
                    pv[reg] = p;
                }
                lpart += ps;
                unsigned p01 = pk2(pv[0], pv[1]);
                unsigned p23 = pk2(pv[2], pv[3]);
                *(uint2*)&Pw[L * 72 + nt * 16 + Q * 4] = make_uint2(p01, p23);
            }

            // ---- O += P V (P A-frag wave-private; V B-frag from LDS)
            bf16x8 pf0 = *(const bf16x8*)&Pw[L * 72 + Q * 8];
            bf16x8 pf1 = *(const bf16x8*)&Pw[L * 72 + 32 + Q * 8];
#pragma unroll
            for (int dt = 0; dt < 4; ++dt) {
                int r = dt * 16 + L;
                bf16x8 vf0 = *(const bf16x8*)(Vs + (r * 16 + ((jh * 8 + Q) ^ L)) * 8);
                bf16x8 vf1 = *(const bf16x8*)(Vs + (r * 16 + ((jh * 8 + 4 + Q) ^ L)) * 8);
                accO[dt] = __builtin_amdgcn_mfma_f32_16x16x32_bf16(pf0, vf0, accO[dt], 0, 0, 0);
                accO[dt] = __builtin_amdgcn_mfma_f32_16x16x32_bf16(pf1, vf1, accO[dt], 0, 0, 0);
            }
        }
    }

    // ---- l: in-lane partial + cross-quad shfl; per-row values via shfl
    lpart += __shfl_xor(lpart, 16, 64);
    lpart += __shfl_xor(lpart, 32, 64);
    float linv[4];
#pragma unroll
    for (int reg = 0; reg < 4; ++reg)
        linv[reg] = 1.0f / __shfl(lpart, Q * 4 + reg, 64);

    // O C-layout: col = d = L, row = i-local = Q*4+reg
#pragma unroll
    for (int reg = 0; reg < 4; ++reg) {
        const size_t row = (size_t)b * NSeq + iw + Q * 4 + reg;
#pragma unroll
        for (int dt = 0; dt < 4; ++dt)
            aout[row * DIM + h * HD + dt * 16 + L] = f2b(accO[dt][reg] * linv[reg]);
    }
}

// ---------------------------------------------------------------------------
extern "C" void kernel_launch(void* const* d_in, const int* in_sizes, int n_in,
                              void* d_out, int out_size, void* d_ws, size_t ws_size,
                              hipStream_t stream)
{
    const float* x      = (const float*)d_in[0];
    const float* coords = (const float*)d_in[1];
    const float* elevp  = (const float*)d_in[2];
    const float* Wqkv   = (const float*)d_in[3];
    const float* Wproj  = (const float*)d_in[4];
    const float* bproj  = (const float*)d_in[5];
    const float* btab   = (const float*)d_in[6];
    const float* alpha  = (const float*)d_in[7];
    float* out = (float*)d_out;

    char* ws = (char*)d_ws;
    short* xb     = (short*)(ws);                        // 4096x768 bf16
    short* wqkvT  = (short*)(ws + 6291456);              // 2304x768 bf16
    short* wprojT = (short*)(ws + 9830400);              // 768x768 bf16
    short* qh     = (short*)(ws + 11010048);             // [48][1024][64]
    short* kh     = (short*)(ws + 17301504);
    short* vt     = (short*)(ws + 23592960);             // [48][64][1024]
    short* aout   = (short*)(ws + 29884416);             // 4096x768 bf16
    unsigned int* U = (unsigned int*)(ws + 36175872);    // 16.78 MB packed bias
    // total ws use: 52,953,088 bytes

    const int M = 4 * NSeq;

    prep_kernel<<<dim3(PREP_TOT), 256, 0, stream>>>(
        x, xb, Wqkv, wqkvT, Wproj, wprojT, coords, elevp, alpha, U);

    gemm_mfma<0><<<dim3(3 * DIM / 128, M / 64), 256, 0, stream>>>(
        xb, wqkvT, nullptr, nullptr, qh, kh, vt, M, 3 * DIM, DIM);

    attn_mfma<<<dim3(NSeq / 64, 4 * NH), 256, 0, stream>>>(
        qh, kh, vt, U, btab, aout);

    gemm_mfma<1><<<dim3(DIM / 128, M / 64), 256, 0, stream>>>(
        aout, wprojT, bproj, out, nullptr, nullptr, nullptr, M, DIM, DIM);
}

// Round 9
// 174.594 us; speedup vs baseline: 1.5970x; 1.1638x over previous
//
#include <hip/hip_runtime.h>
#include <hip/hip_bf16.h>
#include <math.h>

// Shapes: B=4, N=1024, D=768, H=12, hd=64
constexpr int NSeq = 1024;
constexpr int DIM  = 768;
constexpr int NH   = 12;
constexpr int HD   = 64;

// exp2-domain softmax constants
#define LOG2E     1.4426950408889634f
#define QSCALE    0.18033688011112042f   /* 0.125 * log2e */
#define BSHIFT    11.541560327111707f    /* 8 * log2e */
#define EBQ       6551.278150676693f     /* log2e * 4541 (16-bit quant scale) */
#define EBDEC     (-1.0f / 4541.0f)

#if __has_builtin(__builtin_amdgcn_exp2f)
#define EXP2F(x) __builtin_amdgcn_exp2f(x)
#else
#define EXP2F(x) exp2f(x)
#endif

typedef __attribute__((ext_vector_type(8))) short bf16x8;   // 8 bf16 (4 VGPRs)
typedef __attribute__((ext_vector_type(4))) float f32x4;

// fp32 -> bf16 RNE (scalar)
__device__ __forceinline__ short f2b(float f) {
    unsigned u = __float_as_uint(f);
    unsigned r = (u + 0x7fffu + ((u >> 16) & 1u)) >> 16;
    return (short)r;
}
// packed pair via native v_cvt_pk_bf16_f32
__device__ __forceinline__ unsigned pk2(float a, float b) {
    __hip_bfloat162 h = __float22bfloat162_rn(float2{a, b});
    return *reinterpret_cast<unsigned*>(&h);
}

// async global->LDS, 16B per lane. LDS dest = uniform base + lane*16.
__device__ __forceinline__ void glds16(const short* g, short* l) {
    __builtin_amdgcn_global_load_lds(
        (const __attribute__((address_space(1))) void*)g,
        (__attribute__((address_space(3))) void*)l, 16, 0, 0);
}

// T5 bucket, integer-exact thresholds (validated round 1)
__device__ __forceinline__ int rel_bucket(int rel) {
    int n = -rel;
    int ret = (n < 0) ? 16 : 0;
    n = (n < 0) ? -n : n;
    int k;
    if (n < 8) {
        k = n;
    } else {
        k = 8 + (n >= 12) + (n >= 16) + (n >= 23) + (n >= 32)
              + (n >= 46) + (n >= 64) + (n >= 91);
        if (k > 15) k = 15;
    }
    return ret + k;
}

// ---------------------------------------------------------------------------
// Fused prep. Ranges (re-derived, R8 crash was a bad cast-range offset):
//   upack      [0, 2048)          : (b,i16,jt-pair) spread for occupancy
//   cast       [2048, 5120)       : idx = bx - 2048, 3072 blocks x 1024 elems
//   transposes [5120, 5696)       : 576 blocks x 4 tiles (Wqkv 1728 + Wproj 576)
constexpr int PREP_UP   = 2048;
constexpr int PREP_CE   = PREP_UP + 3072;     // 5120 cast end
constexpr int PREP_TOT  = PREP_CE + 576;      // 5696

__global__ __launch_bounds__(256) void prep_kernel(
    const float* __restrict__ x, short* __restrict__ xb,
    const float* __restrict__ Wqkv, short* __restrict__ wqkvT,
    const float* __restrict__ Wproj, short* __restrict__ wprojT,
    const float* __restrict__ coords, const float* __restrict__ elev,
    const float* __restrict__ alpha_p, unsigned int* __restrict__ U)
{
    __shared__ float t[32][33];
    const int bx  = blockIdx.x;
    const int tid = threadIdx.x;

    if (bx < PREP_UP) {
        // ---- upack: bx -> (b, i16, jtp); wave w: jt = jtp*2+(w>>1), nt-half w&1
        const int b    = bx >> 9;
        const int rem  = bx & 511;
        const int i16  = rem >> 3;
        const int jtp  = rem & 7;
        const int blk  = b * 64 + i16;
        const int lane = tid & 63, wv = tid >> 6;
        const int L = lane & 15, Q = lane >> 4;
        const float alpha = alpha_p[0];

        const int i = (i16 << 4) + L;
        const float2 cf = *(const float2*)&coords[(((size_t)b << 10) + i) * 2];
        const int cix = (int)(cf.x * 128.0f);
        const int ciy = (int)(cf.y * 128.0f);
        const float er = elev[((size_t)b << 10) + i];
        const int jt = jtp * 2 + (wv >> 1);
#pragma unroll
        for (int nth = 0; nth < 2; ++nth) {
            const int nt = (wv & 1) * 2 + nth;
            const int j0q = jt * 64 + nt * 16 + Q * 4;
            float4 c01 = *(const float4*)&coords[(((size_t)b << 10) + j0q) * 2];
            float4 c23 = *(const float4*)&coords[(((size_t)b << 10) + j0q + 2) * 2];
            float4 ej  = *(const float4*)&elev[((size_t)b << 10) + j0q];
            const float cjx[4] = {c01.x, c01.z, c23.x, c23.z};
            const float cjy[4] = {c01.y, c01.w, c23.y, c23.w};
            const float ejv[4] = {ej.x, ej.y, ej.z, ej.w};
            unsigned int uo[4];
#pragma unroll
            for (int reg = 0; reg < 4; ++reg) {
                int bk = rel_bucket(cix - (int)(cjx[reg] * 128.0f)) * 32
                       + rel_bucket(ciy - (int)(cjy[reg] * 128.0f));
                float ebp = fminf(10.0f,
                    fmaxf(0.0f, alpha * fmaxf((ejv[reg] - er) * 0.001f, 0.0f)));
                unsigned int q = (unsigned int)lrintf(ebp * EBQ);
                uo[reg] = (unsigned int)bk | (q << 16);
            }
            size_t base = ((((size_t)blk * 16 + jt) * 4 + nt) * 64 + lane) * 4;
            *(uint4*)(U + base) = make_uint4(uo[0], uo[1], uo[2], uo[3]);
        }
        return;
    }
    if (bx < PREP_CE) {
        // ---- cast x -> bf16
        int i = ((bx - PREP_UP) * 256 + tid) * 4;
        float4 v = *(const float4*)(x + i);
        *(short4*)(xb + i) = make_short4(f2b(v.x), f2b(v.y), f2b(v.z), f2b(v.w));
        return;
    }
    // ---- weight transposes: 4 tiles per block
    {
        const int bxx = bx - PREP_CE;          // 0..575
#pragma unroll
        for (int tt = 0; tt < 4; ++tt) {
            const int tile = bxx * 4 + tt;     // 0..2303
            const float* W; short* WT; int K, Nw, idx;
            if (tile < 1728) { W = Wqkv;  WT = wqkvT;  K = DIM; Nw = 3 * DIM; idx = tile; }
            else             { W = Wproj; WT = wprojT; K = DIM; Nw = DIM;     idx = tile - 1728; }
            const int ntl = idx % (Nw / 32), ktl = idx / (Nw / 32);
            const int k0 = ktl * 32, n0 = ntl * 32;
            const int tx = tid & 31, ty = tid >> 5;
            __syncthreads();                   // WAR vs previous tile's reads
#pragma unroll
            for (int r = 0; r < 4; ++r)
                t[ty + r * 8][tx] = W[(size_t)(k0 + ty + r * 8) * Nw + n0 + tx];
            __syncthreads();
#pragma unroll
            for (int r = 0; r < 4; ++r)
                WT[(size_t)(n0 + ty + r * 8) * K + k0 + tx] = f2b(t[tx][ty + r * 8]);
        }
    }
}

// ---------------------------------------------------------------------------
// bf16 MFMA GEMM: C = A[M,K] @ BT[N,K]^T. Tile 64(M) x 128(N), BK=64,
// block 256 = 2x2 waves, wave tile 32x64. glds(16B) staging, XOR swizzle.
// EPI=0 epilogue routes through LDS so ALL global stores are full 16B/lane
// lines (R7 scatter: V = 8B/lane at 2KB stride = 64 lines/inst, 16x L2 write
// amplification; Q/K = 32B segments, 4x).
template <int EPI>
__global__ __launch_bounds__(256) void gemm_mfma(
    const short* __restrict__ A, const short* __restrict__ BT,
    const float* __restrict__ bias, float* __restrict__ Cout,
    short* __restrict__ qh, short* __restrict__ kh, short* __restrict__ vt,
    int M, int N, int K)
{
    __shared__ short SH[64 * 64 + 128 * 64];   // As (8 KB) | Bs (16 KB)
    short* As = SH;
    short* Bs = SH + 64 * 64;

    const int tid  = threadIdx.x;
    const int lane = tid & 63;
    const int wave = tid >> 6;
    const int L = lane & 15, Q = lane >> 4;
    const int m0b = blockIdx.y * 64, n0b = blockIdx.x * 128;
    const int mw = (wave >> 1) * 32;
    const int nw = (wave & 1) * 64;

    size_t aoff[2]; int la[2];
#pragma unroll
    for (int t = 0; t < 2; ++t) {
        int s = wave * 128 + t * 64 + lane;
        int r = s >> 3, c = (s & 7) ^ (r & 7);
        aoff[t] = (size_t)(m0b + r) * K + c * 8;
        la[t] = (wave * 128 + t * 64) * 8;
    }
    size_t boff[4]; int lb[4];
#pragma unroll
    for (int t = 0; t < 4; ++t) {
        int s = wave * 256 + t * 64 + lane;
        int r = s >> 3, c = (s & 7) ^ (r & 7);
        boff[t] = (size_t)(n0b + r) * K + c * 8;
        lb[t] = (wave * 256 + t * 64) * 8;
    }

    f32x4 acc[2][4];
#pragma unroll
    for (int i = 0; i < 2; ++i)
#pragma unroll
        for (int j = 0; j < 4; ++j) acc[i][j] = (f32x4){0.f, 0.f, 0.f, 0.f};

    for (int k0 = 0; k0 < K; k0 += 64) {
        __syncthreads();
#pragma unroll
        for (int t = 0; t < 2; ++t) glds16(A + aoff[t] + k0, As + la[t]);
#pragma unroll
        for (int t = 0; t < 4; ++t) glds16(BT + boff[t] + k0, Bs + lb[t]);
        __syncthreads();
#pragma unroll
        for (int ks = 0; ks < 2; ++ks) {
            bf16x8 af[2], bfr[4];
#pragma unroll
            for (int mt = 0; mt < 2; ++mt) {
                int r = mw + mt * 16 + L;
                af[mt] = *(const bf16x8*)(As + (r * 8 + ((ks * 4 + Q) ^ (r & 7))) * 8);
            }
#pragma unroll
            for (int nt = 0; nt < 4; ++nt) {
                int r = nw + nt * 16 + L;
                bfr[nt] = *(const bf16x8*)(Bs + (r * 8 + ((ks * 4 + Q) ^ (r & 7))) * 8);
            }
#pragma unroll
            for (int mt = 0; mt < 2; ++mt)
#pragma unroll
                for (int nt = 0; nt < 4; ++nt)
                    acc[mt][nt] = __builtin_amdgcn_mfma_f32_16x16x32_bf16(
                        af[mt], bfr[nt], acc[mt][nt], 0, 0, 0);
        }
    }

    const int m0 = m0b + mw, n0 = n0b + nw;
    if (EPI == 1) {
#pragma unroll
        for (int nt = 0; nt < 4; ++nt) {
            const int col = n0 + nt * 16 + L;
            const float bv = bias[col];
#pragma unroll
            for (int mt = 0; mt < 2; ++mt) {
                const int r0 = m0 + mt * 16 + Q * 4;
#pragma unroll
                for (int reg = 0; reg < 4; ++reg)
                    Cout[(size_t)(r0 + reg) * N + col] = acc[mt][nt][reg] + bv;
            }
        }
    } else {
        // ---- EPI=0: LDS-staged coalesced scatter. Section is block-uniform.
        const int sec   = n0b / DIM;          // 0=Q, 1=K, 2=V
        const int hloc  = (n0b % DIM) >> 6;   // tile spans heads hloc, hloc+1
        const int bidx  = m0b >> 10;
        const int ntok0 = m0b & 1023;
        short* T = SH;
        __syncthreads();                      // all LDS reads of K-loop done

        if (sec < 2) {
            // T[token][col], stride 136
            const float qs = (sec == 0) ? QSCALE : 1.0f;
#pragma unroll
            for (int nt = 0; nt < 4; ++nt)
#pragma unroll
                for (int mt = 0; mt < 2; ++mt) {
                    int tok = mw + mt * 16 + Q * 4;
                    int col = nw + nt * 16 + L;
#pragma unroll
                    for (int reg = 0; reg < 4; ++reg)
                        T[(tok + reg) * 136 + col] = f2b(acc[mt][nt][reg] * qs);
                }
            __syncthreads();
            // read-back: thread -> (hh, token, half); 4x 16B line-stores
            const int pr = tid >> 1, half = tid & 1;
            const int hh = pr >> 6, tok = pr & 63;
            short* dstb = (sec == 0 ? qh : kh)
                + (((size_t)bidx * NH + hloc + hh) * NSeq + ntok0 + tok) * HD + half * 32;
            const short* srcb = T + tok * 136 + hh * 64 + half * 32;
#pragma unroll
            for (int c = 0; c < 4; ++c)
                *(bf16x8*)(dstb + c * 8) = *(const bf16x8*)(srcb + c * 8);
        } else {
            // V: T[col][token], stride 72; packed 8B frag writes
#pragma unroll
            for (int nt = 0; nt < 4; ++nt)
#pragma unroll
                for (int mt = 0; mt < 2; ++mt) {
                    int tok = mw + mt * 16 + Q * 4;
                    int col = nw + nt * 16 + L;
                    short4 pv = make_short4(f2b(acc[mt][nt][0]), f2b(acc[mt][nt][1]),
                                            f2b(acc[mt][nt][2]), f2b(acc[mt][nt][3]));
                    *(short4*)&T[col * 72 + tok] = pv;
                }
            __syncthreads();
            const int col = tid >> 1, half = tid & 1;
            const int hh = col >> 6, d = col & 63;
            short* dstb = vt
                + (((size_t)bidx * NH + hloc + hh) * HD + d) * NSeq + ntok0 + half * 32;
            const short* srcb = T + col * 72 + half * 32;
#pragma unroll
            for (int c = 0; c < 4; ++c)
                *(bf16x8*)(dstb + c * 8) = *(const bf16x8*)(srcb + c * 8);
        }
    }
}

// ---------------------------------------------------------------------------
// Transposed-S flash attention (v6.1 structure, unchanged).
__global__ __launch_bounds__(256) void attn_mfma(
    const short* __restrict__ qh, const short* __restrict__ kh,
    const short* __restrict__ vt,
    const unsigned int* __restrict__ U,
    const float* __restrict__ btab_g,             // [1024][12]
    short* __restrict__ aout)                     // [4096][768] bf16
{
    __shared__ short Ks[128 * 64];  // 16 KB, rows=j, 8 chunks/row
    __shared__ short Vs[64 * 128];  // 16 KB, rows=d, 16 chunks/row
    __shared__ float btab[1024];    // 4 KB (pre-scaled: *log2e - 8*log2e)
    __shared__ short P[4][16 * 72]; // 9 KB

    const int tid  = threadIdx.x;
    const int lane = tid & 63, wave = tid >> 6;
    const int L = lane & 15, Q = lane >> 4;
    const int i0 = blockIdx.x * 64;
    const int bh = blockIdx.y;
    const int b  = bh / NH, h = bh % NH;

    for (int p = tid; p < 1024; p += 256)
        btab[p] = btab_g[(size_t)p * NH + h] * LOG2E - BSHIFT;

    const int iw = i0 + wave * 16;

    const short* qbase = qh + ((size_t)bh * NSeq + iw + L) * HD + Q * 8;
    const bf16x8 qf0 = *(const bf16x8*)qbase;
    const bf16x8 qf1 = *(const bf16x8*)(qbase + 32);

    size_t kgo[4], vgo[4];
    int lsl[4];
#pragma unroll
    for (int t = 0; t < 4; ++t) {
        int s = wave * 256 + t * 64 + lane;            // 0..1023
        int kr = s >> 3, kc = (s & 7) ^ (kr & 7);
        kgo[t] = ((size_t)bh * NSeq + kr) * HD + kc * 8;       // + j0*HD
        int vr = s >> 4, vc = (s & 15) ^ (vr & 15);
        vgo[t] = ((size_t)bh * HD + vr) * NSeq + vc * 8;       // + j0
        lsl[t] = s * 8;
    }

    const int i16g = (b * 64) + (blockIdx.x * 4 + wave);
    const unsigned int* Ub = U + (size_t)i16g * 16 * 4 * 256 + lane * 4;

    float lpart = 0.0f;
    f32x4 accO[4];
#pragma unroll
    for (int t = 0; t < 4; ++t) accO[t] = (f32x4){0.f, 0.f, 0.f, 0.f};

    short* Pw = P[wave];

    for (int jt = 0; jt < 8; ++jt) {
        const int j0 = jt * 128;
        __syncthreads();
#pragma unroll
        for (int t = 0; t < 4; ++t) glds16(kh + kgo[t] + (size_t)j0 * HD, Ks + lsl[t]);
#pragma unroll
        for (int t = 0; t < 4; ++t) glds16(vt + vgo[t] + j0, Vs + lsl[t]);
        __syncthreads();

#pragma unroll
        for (int jh = 0; jh < 2; ++jh) {
            f32x4 st[4];
#pragma unroll
            for (int nt = 0; nt < 4; ++nt) {
                int r = jh * 64 + nt * 16 + L;
                bf16x8 kf0 = *(const bf16x8*)(Ks + (r * 8 + (Q ^ (L & 7))) * 8);
                bf16x8 kf1 = *(const bf16x8*)(Ks + (r * 8 + ((4 + Q) ^ (L & 7))) * 8);
                f32x4 z = (f32x4){0.f, 0.f, 0.f, 0.f};
                z = __builtin_amdgcn_mfma_f32_16x16x32_bf16(kf0, qf0, z, 0, 0, 0);
                st[nt] = __builtin_amdgcn_mfma_f32_16x16x32_bf16(kf1, qf1, z, 0, 0, 0);
            }

#pragma unroll
            for (int nt = 0; nt < 4; ++nt) {
                uint4 u = *(const uint4*)(Ub + (((size_t)jt * 2 + jh) * 4 + nt) * 256);
                const unsigned int uv[4] = {u.x, u.y, u.z, u.w};
                float pv[4];
                float ps = 0.0f;
#pragma unroll
                for (int reg = 0; reg < 4; ++reg) {
                    float arg = st[nt][reg] + btab[uv[reg] & 1023];
                    arg = fmaf((float)(uv[reg] >> 16), EBDEC, arg);
                    float p = EXP2F(arg);
                    ps += p;
                    pv[reg] = p;
                }
                lpart += ps;
                unsigned p01 = pk2(pv[0], pv[1]);
                unsigned p23 = pk2(pv[2], pv[3]);
                *(uint2*)&Pw[L * 72 + nt * 16 + Q * 4] = make_uint2(p01, p23);
            }

            bf16x8 pf0 = *(const bf16x8*)&Pw[L * 72 + Q * 8];
            bf16x8 pf1 = *(const bf16x8*)&Pw[L * 72 + 32 + Q * 8];
#pragma unroll
            for (int dt = 0; dt < 4; ++dt) {
                int r = dt * 16 + L;
                bf16x8 vf0 = *(const bf16x8*)(Vs + (r * 16 + ((jh * 8 + Q) ^ L)) * 8);
                bf16x8 vf1 = *(const bf16x8*)(Vs + (r * 16 + ((jh * 8 + 4 + Q) ^ L)) * 8);
                accO[dt] = __builtin_amdgcn_mfma_f32_16x16x32_bf16(pf0, vf0, accO[dt], 0, 0, 0);
                accO[dt] = __builtin_amdgcn_mfma_f32_16x16x32_bf16(pf1, vf1, accO[dt], 0, 0, 0);
            }
        }
    }

    lpart += __shfl_xor(lpart, 16, 64);
    lpart += __shfl_xor(lpart, 32, 64);
    float linv[4];
#pragma unroll
    for (int reg = 0; reg < 4; ++reg)
        linv[reg] = 1.0f / __shfl(lpart, Q * 4 + reg, 64);

#pragma unroll
    for (int reg = 0; reg < 4; ++reg) {
        const size_t row = (size_t)b * NSeq + iw + Q * 4 + reg;
#pragma unroll
        for (int dt = 0; dt < 4; ++dt)
            aout[row * DIM + h * HD + dt * 16 + L] = f2b(accO[dt][reg] * linv[reg]);
    }
}

// ---------------------------------------------------------------------------
extern "C" void kernel_launch(void* const* d_in, const int* in_sizes, int n_in,
                              void* d_out, int out_size, void* d_ws, size_t ws_size,
                              hipStream_t stream)
{
    const float* x      = (const float*)d_in[0];
    const float* coords = (const float*)d_in[1];
    const float* elevp  = (const float*)d_in[2];
    const float* Wqkv   = (const float*)d_in[3];
    const float* Wproj  = (const float*)d_in[4];
    const float* bproj  = (const float*)d_in[5];
    const float* btab   = (const float*)d_in[6];
    const float* alpha  = (const float*)d_in[7];
    float* out = (float*)d_out;

    char* ws = (char*)d_ws;
    short* xb     = (short*)(ws);                        // 4096x768 bf16
    short* wqkvT  = (short*)(ws + 6291456);              // 2304x768 bf16
    short* wprojT = (short*)(ws + 9830400);              // 768x768 bf16
    short* qh     = (short*)(ws + 11010048);             // [48][1024][64]
    short* kh     = (short*)(ws + 17301504);
    short* vt     = (short*)(ws + 23592960);             // [48][64][1024]
    short* aout   = (short*)(ws + 29884416);             // 4096x768 bf16
    unsigned int* U = (unsigned int*)(ws + 36175872);    // 16.78 MB packed bias
    // total ws use: 52,953,088 bytes

    const int M = 4 * NSeq;

    prep_kernel<<<dim3(PREP_TOT), 256, 0, stream>>>(
        x, xb, Wqkv, wqkvT, Wproj, wprojT, coords, elevp, alpha, U);

    gemm_mfma<0><<<dim3(3 * DIM / 128, M / 64), 256, 0, stream>>>(
        xb, wqkvT, nullptr, nullptr, qh, kh, vt, M, 3 * DIM, DIM);

    attn_mfma<<<dim3(NSeq / 64, 4 * NH), 256, 0, stream>>>(
        qh, kh, vt, U, btab, aout);

    gemm_mfma<1><<<dim3(DIM / 128, M / 64), 256, 0, stream>>>(
        aout, wprojT, bproj, out, nullptr, nullptr, nullptr, M, DIM, DIM);
}